// Round 1
// baseline (121.315 us; speedup 1.0000x reference)
//
#include <hip/hip_runtime.h>

// RelativePositionEncoding: out[i,j,c] = (Wpos[dp[i,j],c] + Wtok[dt[i,j],c]
//   + same_ent[i,j]*Went[c] + Wchain[dc[i,j],c]) * mask[i]*mask[j]
// N=1024, C=128, table rows = 2*66 + 6 + 1 = 139 (+1 zero row).
// Memory-bound: 512 MiB f32 output stream. Table staged in LDS (71.7 KB).

#define N_TOK 1024
#define C_PAIR 128
#define NR 66            // 2*R_MAX + 2
#define NS 6             // 2*S_MAX + 2
#define W_COLS 139       // 2*NR + NS + 1
#define ROWS 140         // 139 + one zero row (for same_entity==false)

__global__ __launch_bounds__(1024, 8)
void relpos_kernel(const int* __restrict__ ri, const int* __restrict__ ti,
                   const int* __restrict__ ai, const int* __restrict__ ei,
                   const float* __restrict__ mask, const float* __restrict__ W,
                   float* __restrict__ out, int nblocks_stride) {
    __shared__ float wt[ROWS * C_PAIR];  // wt[k][c] = W[c][k]; row 139 = zeros

    // One-time transpose-load of W into LDS (71 KB, L2/L3-absorbed re-reads).
    for (int idx = threadIdx.x; idx < ROWS * C_PAIR; idx += blockDim.x) {
        int k = idx >> 7;        // row  (0..139)
        int c = idx & 127;       // channel
        wt[idx] = (k < W_COLS) ? W[c * W_COLS + k] : 0.0f;
    }
    __syncthreads();

    const int total = N_TOK * N_TOK * (C_PAIR / 4);  // float4 items = 33,554,432
    const int stride = nblocks_stride;               // gridDim.x * blockDim.x
    float4* __restrict__ out4 = (float4*)out;

    for (int g = blockIdx.x * blockDim.x + threadIdx.x; g < total; g += stride) {
        int c4   = g & 31;          // which float4 of the 128 channels
        int pair = g >> 5;
        int j = pair & (N_TOK - 1);
        int i = pair >> 10;

        // Pair-uniform scalar loads (L1-resident 4 KB arrays; 2 distinct
        // addresses per wave -> broadcast).
        int   r_i = ri[i], r_j = ri[j];
        int   t_i = ti[i], t_j = ti[j];
        int   a_i = ai[i], a_j = ai[j];
        int   e_i = ei[i], e_j = ei[j];
        float m   = mask[i] * mask[j];

        bool same_chain = (a_i == a_j);
        bool same_res   = (r_i == r_j);
        bool same_ent   = (e_i == e_j);

        // d[i,j] = feat[j] - feat[i]
        int dp = same_chain              ? min(max(r_j - r_i + 32, 0), 64) : 65;
        int dt = (same_chain && same_res)? min(max(t_j - t_i + 32, 0), 64) : 65;
        int dc = same_chain              ? min(max(a_j - a_i + 2,  0), 4)  : 5;
        int re = same_ent ? (2 * NR) : (ROWS - 1);   // 132 or zero-row 139

        const float4* wp = (const float4*)&wt[dp * C_PAIR];
        const float4* wk = (const float4*)&wt[(NR + dt) * C_PAIR];
        const float4* we = (const float4*)&wt[re * C_PAIR];
        const float4* wc = (const float4*)&wt[(2 * NR + 1 + dc) * C_PAIR];

        float4 a = wp[c4];
        float4 b = wk[c4];
        float4 e = we[c4];
        float4 c = wc[c4];

        float4 v;
        v.x = (a.x + b.x + e.x + c.x) * m;
        v.y = (a.y + b.y + e.y + c.y) * m;
        v.z = (a.z + b.z + e.z + c.z) * m;
        v.w = (a.w + b.w + e.w + c.w) * m;

        out4[g] = v;   // wave writes 1 KB contiguous
    }
}

extern "C" void kernel_launch(void* const* d_in, const int* in_sizes, int n_in,
                              void* d_out, int out_size, void* d_ws, size_t ws_size,
                              hipStream_t stream) {
    const int*   ri   = (const int*)d_in[0];
    const int*   ti   = (const int*)d_in[1];
    const int*   ai   = (const int*)d_in[2];
    const int*   ei   = (const int*)d_in[3];
    const float* mask = (const float*)d_in[4];
    const float* W    = (const float*)d_in[5];
    float*       out  = (float*)d_out;

    const int threads = 1024;
    const int blocks  = 512;             // 2 blocks/CU (LDS-limited), 64 iters/thread
    relpos_kernel<<<blocks, threads, 0, stream>>>(ri, ti, ai, ei, mask, W, out,
                                                  blocks * threads);
}

// Round 3
// 115.146 us; speedup vs baseline: 1.0536x; 1.0536x over previous
//
#include <hip/hip_runtime.h>

// RelativePositionEncoding: out[i,j,c] = (Wpos[dp,c] + Wtok[dt,c]
//   + same_ent*Went[c] + Wchain[dc,c]) * mask[i]*mask[j]
// N=1024, C=128. Pure write-stream (512 MiB f32). Table (140x128 f32,
// 71.7 KB incl. zero row) staged in LDS. Each thread computes its pair's
// buckets ONCE and emits 64 B (4x float4) via non-temporal stores.

#define N_TOK 1024
#define C_PAIR 128
#define NR 66            // 2*R_MAX + 2
#define NS 6             // 2*S_MAX + 2
#define W_COLS 139       // 2*NR + NS + 1
#define ROWS 140         // 139 + one zero row (same_entity==false)

typedef float f32x4 __attribute__((ext_vector_type(4)));   // native vec for nt-store

__global__ __launch_bounds__(1024, 8)
void relpos_kernel(const int* __restrict__ ri, const int* __restrict__ ti,
                   const int* __restrict__ ai, const int* __restrict__ ei,
                   const float* __restrict__ mask, const float* __restrict__ W,
                   float* __restrict__ out) {
    __shared__ float wt[ROWS * C_PAIR];  // wt[k][c] = W[c][k]; row 139 = zeros

    // Coalesced read of W [128][139]; transposed write into LDS (startup only).
    for (int idx = threadIdx.x; idx < C_PAIR * W_COLS; idx += blockDim.x) {
        int c = idx / W_COLS;            // compiler magic-mul
        int k = idx - c * W_COLS;
        wt[k * C_PAIR + c] = W[idx];
    }
    for (int idx = threadIdx.x; idx < C_PAIR; idx += blockDim.x)
        wt[(ROWS - 1) * C_PAIR + idx] = 0.0f;
    __syncthreads();

    const int total  = N_TOK * N_TOK * 8;          // 64-B items = 8,388,608
    const int stride = gridDim.x * blockDim.x;     // 524,288 -> 16 iters/thread
    f32x4* __restrict__ out4 = (f32x4*)out;

    for (int t = blockIdx.x * blockDim.x + threadIdx.x; t < total; t += stride) {
        int c4   = t & 7;                // base float4 slot; writes c4+{0,8,16,24}
        int pair = t >> 3;
        int j = pair & (N_TOK - 1);
        int i = pair >> 10;

        // 8-lane groups share (i,j) -> <=8 distinct addrs/wave, L1-resident.
        int   r_i = ri[i], r_j = ri[j];
        int   t_i = ti[i], t_j = ti[j];
        int   a_i = ai[i], a_j = ai[j];
        int   e_i = ei[i], e_j = ei[j];
        float m   = mask[i] * mask[j];

        bool same_chain = (a_i == a_j);
        bool same_res   = (r_i == r_j);

        // d[i,j] = feat[j] - feat[i]
        int dp = same_chain               ? min(max(r_j - r_i + 32, 0), 64) : 65;
        int dt = (same_chain && same_res) ? min(max(t_j - t_i + 32, 0), 64) : 65;
        int dc = same_chain               ? min(max(a_j - a_i + 2,  0), 4)  : 5;
        int re = (e_i == e_j) ? (2 * NR) : (ROWS - 1);   // 132 or zero row

        const f32x4* wp = (const f32x4*)&wt[dp * C_PAIR];
        const f32x4* wk = (const f32x4*)&wt[(NR + dt) * C_PAIR];
        const f32x4* we = (const f32x4*)&wt[re * C_PAIR];
        const f32x4* wc = (const f32x4*)&wt[(2 * NR + 1 + dc) * C_PAIR];

        int base = pair * 32 + c4;
        #pragma unroll
        for (int q = 0; q < 4; ++q) {
            int cc = c4 + 8 * q;
            f32x4 v = (wp[cc] + wk[cc] + we[cc] + wc[cc]) * m;
            __builtin_nontemporal_store(v, &out4[base + 8 * q]);
        }
    }
}

extern "C" void kernel_launch(void* const* d_in, const int* in_sizes, int n_in,
                              void* d_out, int out_size, void* d_ws, size_t ws_size,
                              hipStream_t stream) {
    const int*   ri   = (const int*)d_in[0];
    const int*   ti   = (const int*)d_in[1];
    const int*   ai   = (const int*)d_in[2];
    const int*   ei   = (const int*)d_in[3];
    const float* mask = (const float*)d_in[4];
    const float* W    = (const float*)d_in[5];
    float*       out  = (float*)d_out;

    const int threads = 1024;
    const int blocks  = 512;   // 2 blocks/CU (71.7 KB LDS), 16 iters/thread
    relpos_kernel<<<blocks, threads, 0, stream>>>(ri, ti, ai, ei, mask, W, out);
}